// Round 1
// baseline (816.748 us; speedup 1.0000x reference)
//
#include <hip/hip_runtime.h>

// Problem constants (B=8, C=64, W=496, H=432)
#define WH      214272   // 496*432 pixels per (b,c) plane
#define GPB     53568    // WH/4  float4 groups per plane (and per-batch pixel groups)
#define NPLANE  512      // B*C planes
#define NGROUP  (8*GPB)  // total pixel groups over (b, pixel/4) = 428544

// ---------------- K1: per-channel sum / sumsq + per-batch mask count ----------------
__global__ __launch_bounds__(256) void k_stats(const float4* __restrict__ x4,
                                               float* __restrict__ gsum,
                                               float* __restrict__ gsq,
                                               int* __restrict__ gn) {
    __shared__ float lsum[64];
    __shared__ float lsq[64];
    __shared__ int   ln[8];
    const int tid = threadIdx.x;
    if (tid < 64) { lsum[tid] = 0.f; lsq[tid] = 0.f; }
    if (tid < 8)  ln[tid] = 0;
    __syncthreads();

    float acc[64];
    float acc2[64];
#pragma unroll
    for (int c = 0; c < 64; ++c) { acc[c] = 0.f; acc2[c] = 0.f; }

    const int stride = gridDim.x * blockDim.x;
    for (int g = blockIdx.x * blockDim.x + tid; g < NGROUP; g += stride) {
        const int b = g / GPB;            // const divisor -> magic mul
        const int r = g - b * GPB;
        const float4* p = x4 + (b * 64) * GPB + r;
        float sx = 0.f, sy = 0.f, sz = 0.f, sw = 0.f; // per-pixel channel sums
#pragma unroll
        for (int c = 0; c < 64; ++c) {
            const float4 v = p[c * GPB];
            sx += v.x; sy += v.y; sz += v.z; sw += v.w;
            acc[c] += (v.x + v.y) + (v.z + v.w);
            acc2[c] = fmaf(v.w, v.w, fmaf(v.z, v.z, fmaf(v.y, v.y, fmaf(v.x, v.x, acc2[c]))));
        }
        const int cnt = (sx != 0.f) + (sy != 0.f) + (sz != 0.f) + (sw != 0.f);
        if (cnt) atomicAdd(&ln[b], cnt);
    }

    // 64-lane butterfly reduce each channel; lane L keeps channel L's wave total
    const int lane = tid & 63;
    float mysum = 0.f, mysq = 0.f;
#pragma unroll
    for (int c = 0; c < 64; ++c) {
        float r1 = acc[c], r2 = acc2[c];
#pragma unroll
        for (int m = 1; m < 64; m <<= 1) {
            r1 += __shfl_xor(r1, m, 64);
            r2 += __shfl_xor(r2, m, 64);
        }
        if (lane == c) { mysum = r1; mysq = r2; }
    }
    atomicAdd(&lsum[lane], mysum);  // 4 waves combine in LDS
    atomicAdd(&lsq[lane], mysq);
    __syncthreads();
    if (tid < 64)       atomicAdd(&gsum[tid], lsum[tid]);
    else if (tid < 128) atomicAdd(&gsq[tid - 64], lsq[tid - 64]);
    else if (tid < 136) atomicAdd(&gn[tid - 128], ln[tid - 128]);
}

// ---------------- K2: finalize mean/var -> inv[64] ----------------
__global__ void k_finalize(const float* __restrict__ x,
                           const float* __restrict__ gsum,
                           const float* __restrict__ gsq,
                           const int* __restrict__ gn,
                           float* __restrict__ ginv) {
    const int c = threadIdx.x;   // 64 threads
    int nb[8];
    int N = 0;
#pragma unroll
    for (int b = 0; b < 8; ++b) { nb[b] = gn[b]; N = max(N, nb[b]); }
    float total = gsum[c];
    float S2    = gsq[c];
#pragma unroll
    for (int b = 0; b < 8; ++b) {
        const float pad = (float)(N - nb[b]);
        const float x00 = x[(size_t)(b * 64 + c) * WH];
        total = fmaf(pad, x00, total);
        S2    = fmaf(pad, x00 * x00, S2);
    }
    const float count = (float)(8 * N);
    const float mean  = total / count;
    const float var   = S2 / count - mean * mean;
    ginv[c] = 1.0f / sqrtf(var + 0.001f);
}

// ---------------- K3: out = x * inv[c]  (pure elementwise scale) ----------------
__global__ __launch_bounds__(256) void k_scale(const float4* __restrict__ x4,
                                               float4* __restrict__ out4,
                                               const float* __restrict__ ginv) {
    const int p = blockIdx.x * 256 + threadIdx.x;
    if (p >= GPB) return;
    const int plane = blockIdx.y;            // [0, 512)
    const float inv = ginv[plane & 63];
    const int idx = plane * GPB + p;
    float4 v = x4[idx];
    v.x *= inv; v.y *= inv; v.z *= inv; v.w *= inv;
    out4[idx] = v;
}

extern "C" void kernel_launch(void* const* d_in, const int* in_sizes, int n_in,
                              void* d_out, int out_size, void* d_ws, size_t ws_size,
                              hipStream_t stream) {
    const float* x  = (const float*)d_in[0];
    float* out      = (float*)d_out;
    float* wsf      = (float*)d_ws;
    float* gsum     = wsf;             // 64 floats
    float* gsq      = wsf + 64;        // 64 floats
    int*   gn       = (int*)(wsf + 128); // 8 ints
    float* ginv     = wsf + 136;       // 64 floats

    // zero the accumulators (ws is poisoned 0xAA before every timed launch)
    hipMemsetAsync(d_ws, 0, 136 * sizeof(float), stream);

    k_stats<<<856, 256, 0, stream>>>((const float4*)x, gsum, gsq, gn);
    k_finalize<<<1, 64, 0, stream>>>(x, gsum, gsq, gn, ginv);
    k_scale<<<dim3((GPB + 255) / 256, NPLANE), 256, 0, stream>>>(
        (const float4*)x, (float4*)out, ginv);
}

// Round 2
// 795.199 us; speedup vs baseline: 1.0271x; 1.0271x over previous
//
#include <hip/hip_runtime.h>

// Problem constants (B=8, C=64, W=496, H=432)
#define WH      214272   // 496*432 pixels per (b,c) plane
#define GPB     53568    // WH/4  float4 groups per plane (and per-batch pixel groups)
#define NPLANE  512      // B*C planes
#define NGROUP  (8*GPB)  // total (b, pixel/4) groups = 428544

#define STATS_BLOCKS 856

// ---------------- K1: per-channel sum / sumsq + per-batch mask count ----------------
// Each block = 4 waves; wave w owns channels [16w, 16w+16). All waves iterate the
// same (b, pixel-group) indices: lane-granular grid-stride. 32 accumulator VGPRs
// per thread -> no spill (the round-1 version's 128 spilled to scratch).
// Mask count: occ zeroes ALL channels of a pixel together, so wave 0's 16-channel
// slice determines the mask. b is wave-uniform (GPB % 64 == 0).
__global__ __launch_bounds__(256) void k_stats(const float4* __restrict__ x4,
                                               float* __restrict__ gsum,
                                               float* __restrict__ gsq,
                                               int* __restrict__ gn) {
    const int tid  = threadIdx.x;
    const int lane = tid & 63;
    const int wave = tid >> 6;
    const int c0   = wave * 16;

    float acc[16];
    float acc2[16];
#pragma unroll
    for (int j = 0; j < 16; ++j) { acc[j] = 0.f; acc2[j] = 0.f; }

    const int stride = STATS_BLOCKS * 64;
    for (int i = blockIdx.x * 64 + lane; i < NGROUP; i += stride) {
        const int b = i / GPB;            // wave-uniform (stride & GPB are mult of 64)
        const int r = i - b * GPB;
        const float4* p = x4 + (size_t)(b * 64 + c0) * GPB + r;
        float sx = 0.f, sy = 0.f, sz = 0.f, sw = 0.f;
#pragma unroll
        for (int j = 0; j < 16; ++j) {
            const float4 v = p[(size_t)j * GPB];
            sx += v.x; sy += v.y; sz += v.z; sw += v.w;
            acc[j] += (v.x + v.y) + (v.z + v.w);
            acc2[j] = fmaf(v.w, v.w, fmaf(v.z, v.z, fmaf(v.y, v.y, fmaf(v.x, v.x, acc2[j]))));
        }
        if (wave == 0) {
            int cnt = (sx != 0.f) + (sy != 0.f) + (sz != 0.f) + (sw != 0.f);
#pragma unroll
            for (int m = 1; m < 64; m <<= 1) cnt += __shfl_xor(cnt, m, 64);
            if (lane == 0) atomicAdd(&gn[b], cnt);
        }
    }

    // butterfly-reduce each of the 16 channels across the wave; lane j commits ch c0+j
    float mysum = 0.f, mysq = 0.f;
#pragma unroll
    for (int j = 0; j < 16; ++j) {
        float r1 = acc[j], r2 = acc2[j];
#pragma unroll
        for (int m = 1; m < 64; m <<= 1) {
            r1 += __shfl_xor(r1, m, 64);
            r2 += __shfl_xor(r2, m, 64);
        }
        if (lane == j) { mysum = r1; mysq = r2; }
    }
    if (lane < 16) {
        atomicAdd(&gsum[c0 + lane], mysum);
        atomicAdd(&gsq[c0 + lane], mysq);
    }
}

// ---------------- K2: finalize mean/var -> inv[64] ----------------
__global__ void k_finalize(const float* __restrict__ x,
                           const float* __restrict__ gsum,
                           const float* __restrict__ gsq,
                           const int* __restrict__ gn,
                           float* __restrict__ ginv) {
    const int c = threadIdx.x;   // 64 threads
    int nb[8];
    int N = 0;
#pragma unroll
    for (int b = 0; b < 8; ++b) { nb[b] = gn[b]; N = max(N, nb[b]); }
    float total = gsum[c];
    float S2    = gsq[c];
#pragma unroll
    for (int b = 0; b < 8; ++b) {
        const float pad = (float)(N - nb[b]);
        const float x00 = x[(size_t)(b * 64 + c) * WH];
        total = fmaf(pad, x00, total);
        S2    = fmaf(pad, x00 * x00, S2);
    }
    const float count = (float)(8 * N);
    const float mean  = total / count;
    const float var   = S2 / count - mean * mean;
    ginv[c] = 1.0f / sqrtf(var + 0.001f);
}

// ---------------- K3: out = x * inv[c]  (pure elementwise scale) ----------------
__global__ __launch_bounds__(256) void k_scale(const float4* __restrict__ x4,
                                               float4* __restrict__ out4,
                                               const float* __restrict__ ginv) {
    const int p = blockIdx.x * 256 + threadIdx.x;
    if (p >= GPB) return;
    const int plane = blockIdx.y;            // [0, 512)
    const float inv = ginv[plane & 63];
    const size_t idx = (size_t)plane * GPB + p;
    float4 v = x4[idx];
    v.x *= inv; v.y *= inv; v.z *= inv; v.w *= inv;
    out4[idx] = v;
}

extern "C" void kernel_launch(void* const* d_in, const int* in_sizes, int n_in,
                              void* d_out, int out_size, void* d_ws, size_t ws_size,
                              hipStream_t stream) {
    const float* x  = (const float*)d_in[0];
    float* out      = (float*)d_out;
    float* wsf      = (float*)d_ws;
    float* gsum     = wsf;               // 64 floats
    float* gsq      = wsf + 64;          // 64 floats
    int*   gn       = (int*)(wsf + 128); // 8 ints
    float* ginv     = wsf + 136;         // 64 floats

    hipMemsetAsync(d_ws, 0, 136 * sizeof(float), stream);

    k_stats<<<STATS_BLOCKS, 256, 0, stream>>>((const float4*)x, gsum, gsq, gn);
    k_finalize<<<1, 64, 0, stream>>>(x, gsum, gsq, gn, ginv);
    k_scale<<<dim3((GPB + 255) / 256, NPLANE), 256, 0, stream>>>(
        (const float4*)x, (float4*)out, ginv);
}